// Round 2
// baseline (3245.594 us; speedup 1.0000x reference)
//
#include <hip/hip_runtime.h>
#include <math.h>

#define B_N 64
#define T_N 3072
#define FIN 128
#define TP 1024      // conv output length
#define COUT 64
#define HID 256
#define G4 1024      // 4*HID
#define OUT_N 10
#define NCHUNK 24
#define CHUNK_T (T_N / NCHUNK)   // 128

// w_hh per gate-column: 128 f16x2 dwords = 32 uint4 chunks.
// 24 chunks pinned in AGPRs (24*2cols*4 = 192 AGPRs, asm-pinned so the RA
// cannot remat the loads back into the loop -- the v1/v2 failure mode:
// VGPR_Count=116 proved weights were reloaded from L2 every step, ~3500
// cyc/step of the 5120 measured).
// 8 chunks in LDS (8*1024*16 B = 128 KB).
#define WREG 24
#define WLDS 8

typedef _Float16 h2_t __attribute__((ext_vector_type(2)));
typedef unsigned u32x4 __attribute__((ext_vector_type(4)));
typedef float    f32x4 __attribute__((ext_vector_type(4)));

#if defined(__has_builtin)
#if __has_builtin(__builtin_amdgcn_fdot2)
#define HAVE_FDOT2 1
#endif
#endif

__device__ __forceinline__ float fdot2(unsigned w, unsigned h, float acc) {
#ifdef HAVE_FDOT2
    return __builtin_amdgcn_fdot2(__builtin_bit_cast(h2_t, w),
                                  __builtin_bit_cast(h2_t, h), acc, false);
#else
    h2_t wv = __builtin_bit_cast(h2_t, w), hv = __builtin_bit_cast(h2_t, h);
    return acc + (float)wv.x * (float)hv.x + (float)wv.y * (float)hv.y;
#endif
}

__device__ __forceinline__ unsigned pack2(float a, float b) {
    unsigned la = (unsigned)__builtin_bit_cast(unsigned short, (_Float16)a);
    unsigned lb = (unsigned)__builtin_bit_cast(unsigned short, (_Float16)b);
    return la | (lb << 16);
}

// Gate-column -> storage-slot permutation. Lane-pair layout in lstm_kernel:
// even slot 2m   <- col m        (i-gate, unit m)   [and +512: g-gate]
// odd  slot 2m+1 <- col 256+m    (f-gate, unit m)   [and +512: o-gate]
__device__ __forceinline__ int gperm(int c) {
    int sub = (c >> 9) & 1;      // c >= 512 (g/o half)
    int cc  = c & 511;
    int slot = (cc < 256) ? (cc << 1) : (((cc - 256) << 1) | 1);
    return slot | (sub << 9);
}

// lane-pair swap via DPP quad_perm [1,0,3,2]
__device__ __forceinline__ float swap1(float x) {
    int i = __builtin_bit_cast(int, x);
#if defined(__has_builtin)
#if __has_builtin(__builtin_amdgcn_mov_dpp)
    int r = __builtin_amdgcn_mov_dpp(i, 0xB1, 0xF, 0xF, true);
#else
    int r = __shfl_xor(i, 1, 64);
#endif
#else
    int r = __shfl_xor(i, 1, 64);
#endif
    return __builtin_bit_cast(float, r);
}

// ---------------------------------------------------------------------------
// Pack w_hh to f16x2 chunk layout [chunk c][slot] (uint4 granules, gperm'd
// column order) and build wihT[k][1024] fp32 (ORIGINAL col order) for x_gemm.
// grid 1024 (col), 128 thr (d).
// ---------------------------------------------------------------------------
__global__ void pack_weights(const float* __restrict__ w_ih,
                             const float* __restrict__ w_hh,
                             unsigned* __restrict__ whhR,   // [24][1024] uint4, flat dwords
                             unsigned* __restrict__ whhL,   // [8][1024] uint4, flat dwords
                             float* __restrict__ wihT) {    // [64][1024]
    int col = blockIdx.x, d = threadIdx.x;   // d = packed dword 0..127
    int pcol = gperm(col);
    const float* wr = w_hh + col * HID;
    unsigned p = pack2(wr[2 * d], wr[2 * d + 1]);
    int c = d >> 2, r = d & 3;
    if (c < WREG) whhR[(c * 1024 + pcol) * 4 + r] = p;
    else          whhL[((c - WREG) * 1024 + pcol) * 4 + r] = p;
    if (d < COUT) wihT[d * 1024 + col] = w_ih[col * COUT + d];
}

// conv weight permute: wc2[j][oc], j = kk*128+ic
__global__ void prep_conv_w(const float* __restrict__ conv_w, float* __restrict__ wc2) {
    int i = blockIdx.x * 256 + threadIdx.x;
    if (i < 24576) {
        int j = i >> 6, oc = i & 63;
        int kk = j >> 7, ic = j & 127;
        wc2[i] = conv_w[(oc * 128 + ic) * 3 + kk];
    }
}

// ---------------------------------------------------------------------------
// partial sum-of-squares over time (F.normalize along dim=1)
// ---------------------------------------------------------------------------
__global__ void norm_partial(const float* __restrict__ in, float* __restrict__ part) {
    int b = blockIdx.x, ch = blockIdx.y, f = threadIdx.x;
    const float* p = in + ((size_t)b * T_N + (size_t)ch * CHUNK_T) * FIN + f;
    float s0 = 0.f, s1 = 0.f, s2 = 0.f, s3 = 0.f;
#pragma unroll
    for (int r = 0; r < CHUNK_T; r += 4) {
        float v0 = p[(r + 0) * FIN];
        float v1 = p[(r + 1) * FIN];
        float v2 = p[(r + 2) * FIN];
        float v3 = p[(r + 3) * FIN];
        s0 += v0 * v0; s1 += v1 * v1; s2 += v2 * v2; s3 += v3 * v3;
    }
    part[(b * NCHUNK + ch) * FIN + f] = (s0 + s1) + (s2 + s3);
}

// ---------------------------------------------------------------------------
// normalize + conv1d(k=3,stride=3) + bias + relu  (stride==K -> GEMM)
// ---------------------------------------------------------------------------
__global__ __launch_bounds__(256) void conv_relu(
        const float* __restrict__ in, const float* __restrict__ part,
        const float* __restrict__ wc2, const float* __restrict__ cb,
        float* __restrict__ X) {
    __shared__ __align__(16) float xs[16 * 384];
    __shared__ __align__(16) float wsh[96 * 64];
    __shared__ float invn[FIN];

    int b = blockIdx.x, tile = blockIdx.y;
    int tid = threadIdx.x;

    if (tid < FIN) {
        float s = 0.f;
#pragma unroll
        for (int c = 0; c < NCHUNK; c++) s += part[(b * NCHUNK + c) * FIN + tid];
        invn[tid] = rsqrtf(fmaxf(s, 1e-24f));
    }
    __syncthreads();

    const float* ip = in + ((size_t)b * T_N + (size_t)tile * 48) * FIN;
    for (int i = tid; i < 6144; i += 256) xs[i] = ip[i] * invn[i & 127];

    int oc = tid & 63, tq = tid >> 6;
    float acc0 = 0.f, acc1 = 0.f, acc2 = 0.f, acc3 = 0.f;
    const float* xb = xs + tq * 4 * 384;

    for (int c = 0; c < 4; c++) {
        __syncthreads();
        for (int i = tid; i < 6144; i += 256) wsh[i] = wc2[c * 6144 + i];
        __syncthreads();
#pragma unroll 8
        for (int jj = 0; jj < 96; jj += 4) {
            int j = c * 96 + jj;
            float w0 = wsh[(jj + 0) * 64 + oc];
            float w1 = wsh[(jj + 1) * 64 + oc];
            float w2 = wsh[(jj + 2) * 64 + oc];
            float w3 = wsh[(jj + 3) * 64 + oc];
            float4 x0 = *(const float4*)(xb + j);
            float4 x1 = *(const float4*)(xb + 384 + j);
            float4 x2 = *(const float4*)(xb + 768 + j);
            float4 x3 = *(const float4*)(xb + 1152 + j);
            acc0 += w0 * x0.x + w1 * x0.y + w2 * x0.z + w3 * x0.w;
            acc1 += w0 * x1.x + w1 * x1.y + w2 * x1.z + w3 * x1.w;
            acc2 += w0 * x2.x + w1 * x2.y + w2 * x2.z + w3 * x2.w;
            acc3 += w0 * x3.x + w1 * x3.y + w2 * x3.z + w3 * x3.w;
        }
    }
    float bb = cb[oc];
    int tp0 = tile * 16 + tq * 4;
    size_t o = ((size_t)b * TP + tp0) * COUT + oc;
    X[o]       = fmaxf(acc0 + bb, 0.f);
    X[o + 64]  = fmaxf(acc1 + bb, 0.f);
    X[o + 128] = fmaxf(acc2 + bb, 0.f);
    X[o + 192] = fmaxf(acc3 + bb, 0.f);
}

// ---------------------------------------------------------------------------
// x-projection GEMM: gate[b,t,c] = X[b,t,:] @ w_ih[c,:] + b_ih[c] + b_hh[c],
// stored f16 at PERMUTED slot gperm(c). v3: all 4 gate columns of unit tid
// fused into ONE k-loop (x-tile read once, as aligned float4), ext-vector
// f32 accumulate -> v_pk_fma_f32. grid (64 b, 64 t-tiles of 16), 256 thr.
// ---------------------------------------------------------------------------
__global__ __launch_bounds__(256) void x_gemm(
        const float* __restrict__ X, const float* __restrict__ wihT,
        const float* __restrict__ b_ih, const float* __restrict__ b_hh,
        _Float16* __restrict__ xg) {
    __shared__ __align__(16) float xs[64 * 20];   // [k][r], row stride 20 (80 B, 16B-aligned)
    int b = blockIdx.x, t0 = blockIdx.y * 16, tid = threadIdx.x;

    const float* Xp = X + ((size_t)b * TP + t0) * COUT;
    for (int i = tid; i < 1024; i += 256) {
        int r = i >> 6, k = i & 63;
        xs[k * 20 + r] = Xp[i];
    }
    __syncthreads();

    int cI = tid, cF = tid + 256, cG = tid + 512, cO = tid + 768;
    float bI = b_ih[cI] + b_hh[cI];
    float bF = b_ih[cF] + b_hh[cF];
    float bG = b_ih[cG] + b_hh[cG];
    float bO = b_ih[cO] + b_hh[cO];

    f32x4 aI[4], aF[4], aG[4], aO[4];
#pragma unroll
    for (int q = 0; q < 4; q++) {
        aI[q] = bI; aF[q] = bF; aG[q] = bG; aO[q] = bO;
    }

    for (int k = 0; k < 64; k++) {
        float wI = wihT[k * 1024 + cI];
        float wF = wihT[k * 1024 + cF];
        float wG = wihT[k * 1024 + cG];
        float wO = wihT[k * 1024 + cO];
        const f32x4* xv = (const f32x4*)(xs + k * 20);
#pragma unroll
        for (int q = 0; q < 4; q++) {
            f32x4 x4 = xv[q];
            aI[q] += wI * x4;
            aF[q] += wF * x4;
            aG[q] += wG * x4;
            aO[q] += wO * x4;
        }
    }

    // slots: (2*tid, 2*tid+1) = (i,f); (512+2*tid, 512+2*tid+1) = (g,o)
    unsigned* xgu = (unsigned*)xg;
    size_t base = ((size_t)b * TP + t0) * 512;
#pragma unroll
    for (int r = 0; r < 16; r++) {
        int q = r >> 2, e = r & 3;
        xgu[base + (size_t)r * 512 + tid]       = pack2(aI[q][e], aF[q][e]);
        xgu[base + (size_t)r * 512 + 256 + tid] = pack2(aG[q][e], aO[q][e]);
    }
}

// ---------------------------------------------------------------------------
// Persistent LSTM: 64 blocks x 512 threads, one block/CU, 2 waves/EU pinned.
//
// v3: weights 0..23 pinned in AGPRs via explicit v_accvgpr_write (init) /
// v_accvgpr_read (per use). asm defs are not rematerializable, so the RA
// can NOT reload them from L2 each step (v1/v2 failure: VGPR_Count 116 < 192
// needed, ~3500 cyc/step of L2 weight reloads). AGPR budget: 192 scalar
// AGPRs + ~50 arch VGPRs = ~242 <= 256 @ 2 waves/EU.
//  * h broadcast: 1 ds_read_b64/wave + 128 v_readlane -> SGPR h operands.
//  * lane-pair gates: even lane (i,g), odd lane (f,o), DPP swap, 1 barrier.
// ---------------------------------------------------------------------------
__device__ __forceinline__ float fsig(float x) {
    return 1.f / (1.f + __expf(-x));
}
__device__ __forceinline__ float ftanh(float x) {
    float xc = fminf(fmaxf(x, -15.f), 15.f);
    float e = __expf(2.f * xc);
    return (e - 1.f) / (e + 1.f);
}

#define SM_WL   0
#define SM_H    131072            // two 512 B h buffers (ping-pong)
#define SM_H32  132096            // 256 f32 final h
#define SM_SIZE 133120

#define REP24(M) M(0) M(1) M(2) M(3) M(4) M(5) M(6) M(7) M(8) M(9) M(10) M(11) \
                 M(12) M(13) M(14) M(15) M(16) M(17) M(18) M(19) M(20) M(21) M(22) M(23)
#define REP8(M)  M(0) M(1) M(2) M(3) M(4) M(5) M(6) M(7)

// per-chunk weight dwords pinned in AGPRs (scalar agprs, no alignment needs)
#define DECLW(n)  unsigned wa##n##_0, wa##n##_1, wa##n##_2, wa##n##_3, \
                           wb##n##_0, wb##n##_1, wb##n##_2, wb##n##_3;

#define LOADW(n)  { u32x4 t = whhR4[(n) * 1024 + j]; \
    asm volatile("v_accvgpr_write_b32 %0, %1" : "=a"(wa##n##_0) : "v"(t[0])); \
    asm volatile("v_accvgpr_write_b32 %0, %1" : "=a"(wa##n##_1) : "v"(t[1])); \
    asm volatile("v_accvgpr_write_b32 %0, %1" : "=a"(wa##n##_2) : "v"(t[2])); \
    asm volatile("v_accvgpr_write_b32 %0, %1" : "=a"(wa##n##_3) : "v"(t[3])); \
    t = whhR4[(n) * 1024 + j + 512]; \
    asm volatile("v_accvgpr_write_b32 %0, %1" : "=a"(wb##n##_0) : "v"(t[0])); \
    asm volatile("v_accvgpr_write_b32 %0, %1" : "=a"(wb##n##_1) : "v"(t[1])); \
    asm volatile("v_accvgpr_write_b32 %0, %1" : "=a"(wb##n##_2) : "v"(t[2])); \
    asm volatile("v_accvgpr_write_b32 %0, %1" : "=a"(wb##n##_3) : "v"(t[3])); }

// chunk n covers h dwords 4n..4n+3; dword d lives in lane d>>1, comp d&1
#define DOTCH(n)  { \
    unsigned A0, A1, A2, A3, B0, B1, B2, B3; \
    asm volatile("v_accvgpr_read_b32 %0, %1" : "=v"(A0) : "a"(wa##n##_0)); \
    asm volatile("v_accvgpr_read_b32 %0, %1" : "=v"(B0) : "a"(wb##n##_0)); \
    asm volatile("v_accvgpr_read_b32 %0, %1" : "=v"(A1) : "a"(wa##n##_1)); \
    asm volatile("v_accvgpr_read_b32 %0, %1" : "=v"(B1) : "a"(wb##n##_1)); \
    asm volatile("v_accvgpr_read_b32 %0, %1" : "=v"(A2) : "a"(wa##n##_2)); \
    asm volatile("v_accvgpr_read_b32 %0, %1" : "=v"(B2) : "a"(wb##n##_2)); \
    asm volatile("v_accvgpr_read_b32 %0, %1" : "=v"(A3) : "a"(wa##n##_3)); \
    asm volatile("v_accvgpr_read_b32 %0, %1" : "=v"(B3) : "a"(wb##n##_3)); \
    unsigned h0 = (unsigned)__builtin_amdgcn_readlane((int)hvv.x, 2 * (n)); \
    unsigned h1 = (unsigned)__builtin_amdgcn_readlane((int)hvv.y, 2 * (n)); \
    unsigned h2 = (unsigned)__builtin_amdgcn_readlane((int)hvv.x, 2 * (n) + 1); \
    unsigned h3 = (unsigned)__builtin_amdgcn_readlane((int)hvv.y, 2 * (n) + 1); \
    a0 = fdot2(A0, h0, a0); a1 = fdot2(B0, h0, a1); \
    a0 = fdot2(A1, h1, a0); a1 = fdot2(B1, h1, a1); \
    a0 = fdot2(A2, h2, a0); a1 = fdot2(B2, h2, a1); \
    a0 = fdot2(A3, h3, a0); a1 = fdot2(B3, h3, a1); }

#define DOTLDS(m) { u32x4 WA = wL[(m) * 1024 + j]; u32x4 WB = wL[(m) * 1024 + j + 512]; \
    unsigned h0 = (unsigned)__builtin_amdgcn_readlane((int)hvv.x, 2 * (WREG + (m))); \
    unsigned h1 = (unsigned)__builtin_amdgcn_readlane((int)hvv.y, 2 * (WREG + (m))); \
    unsigned h2 = (unsigned)__builtin_amdgcn_readlane((int)hvv.x, 2 * (WREG + (m)) + 1); \
    unsigned h3 = (unsigned)__builtin_amdgcn_readlane((int)hvv.y, 2 * (WREG + (m)) + 1); \
    a0 = fdot2(WA[0], h0, a0); a1 = fdot2(WB[0], h0, a1); \
    a0 = fdot2(WA[1], h1, a0); a1 = fdot2(WB[1], h1, a1); \
    a0 = fdot2(WA[2], h2, a0); a1 = fdot2(WB[2], h2, a1); \
    a0 = fdot2(WA[3], h3, a0); a1 = fdot2(WB[3], h3, a1); }

__global__ __attribute__((amdgpu_flat_work_group_size(512, 512),
                          amdgpu_waves_per_eu(2, 2)))
void lstm_kernel(
        const u32x4* __restrict__ whhR4, const u32x4* __restrict__ whhL4,
        const _Float16* __restrict__ xg,
        const float* __restrict__ hx0, const float* __restrict__ cx0,
        const float* __restrict__ lin_w, const float* __restrict__ lin_b,
        float* __restrict__ out) {
    extern __shared__ char smem[];
    u32x4*    wL    = (u32x4*)(smem + SM_WL);       // [8][1024] uint4
    _Float16* hbuf  = (_Float16*)(smem + SM_H);     // 2 x 256 (ping-pong)
    float*    h32_s = (float*)(smem + SM_H32);      // 256

    const int b = blockIdx.x, j = threadIdx.x;
    const int lane = j & 63;
    const int m = j >> 1;          // hidden unit owned by this lane pair
    const int odd = j & 1;

    // AGPR-pinned w_hh chunks (192 AGPRs)
    REP24(DECLW)
    REP24(LOADW)

    // stage LDS-resident chunks
    for (int i = j; i < WLDS * 1024; i += 512) wL[i] = whhL4[i];

    float c_reg = 0.f;
    if (odd) c_reg = cx0[b * HID + m];
    if (j < HID) hbuf[j] = (_Float16)hx0[b * HID + j];   // buffer 0 = h(0)

    const _Float16* Xg = xg + (size_t)b * TP * G4;
    _Float16 xa = Xg[j], xb = Xg[j + 512];
    __syncthreads();

    for (int t = 0; t < TP; t++) {
        // gather full h(t) into 2 VGPRs per lane (1 ds_read_b64 / wave)
        const uint2* hp = (const uint2*)(hbuf + (t & 1) * 256);
        uint2 hvv = hp[lane];

        // prefetch next step's x-projection (clamped index; last iter unused)
        int tn = (t + 1 < TP) ? t + 1 : t;
        _Float16 xan = Xg[(size_t)tn * G4 + j];
        _Float16 xbn = Xg[(size_t)tn * G4 + j + 512];

        float a0 = (float)xa, a1 = (float)xb;   // bias folded into xg
        REP24(DOTCH)
        REP8(DOTLDS)

        // even lane: a0=i, a1=g ; odd lane: a0=f, a1=o   (unit m)
        float sa = fsig(a0);            // sig(i) | sig(f)
        float p  = sa * ftanh(a1);      // even: sig(i)*tanh(g)
        float pn = swap1(p);            // odd receives even's product
        if (odd) {
            float so = fsig(a1);        // sig(o)
            c_reg = sa * c_reg + pn;
            float hh = so * ftanh(c_reg);
            hbuf[((t + 1) & 1) * 256 + m] = (_Float16)hh;
            if (t == TP - 1) h32_s[m] = hh;
        }
        __syncthreads();
        xa = xan; xb = xbn;
    }

    // epilogue: out[b] = h @ lin_w.T + lin_b  (fp32 h)
    if (j < OUT_N) {
        float s = lin_b[j];
        const float* lw = lin_w + j * HID;
#pragma unroll 4
        for (int k = 0; k < HID; k++) s += h32_s[k] * lw[k];
        out[b * OUT_N + j] = s;
    }
}

// ---------------------------------------------------------------------------
extern "C" void kernel_launch(void* const* d_in, const int* in_sizes, int n_in,
                              void* d_out, int out_size, void* d_ws, size_t ws_size,
                              hipStream_t stream) {
    const float* input  = (const float*)d_in[0];
    // d_in[1] = r (unused)
    const float* hx0    = (const float*)d_in[2];
    const float* cx0    = (const float*)d_in[3];
    const float* conv_w = (const float*)d_in[4];
    const float* conv_b = (const float*)d_in[5];
    const float* w_ih   = (const float*)d_in[6];
    const float* b_ih   = (const float*)d_in[7];
    const float* w_hh   = (const float*)d_in[8];
    const float* b_hh   = (const float*)d_in[9];
    const float* lin_w  = (const float*)d_in[10];
    const float* lin_b  = (const float*)d_in[11];

    float* ws = (float*)d_ws;
    float*     part = ws;                      // 196608 floats
    float*     X    = part + 196608;           // 4194304 floats
    float*     wc2  = X + 4194304;             // 24576 floats
    float*     wihT = wc2 + 24576;             // 65536 floats
    unsigned*  whhR = (unsigned*)(wihT + 65536);  // 24*1024*4 dwords
    unsigned*  whhL = whhR + WREG * 1024 * 4;     // 8*1024*4 dwords
    _Float16*  xg   = (_Float16*)(whhL + WLDS * 1024 * 4);  // 64*1024*1024 halves

    (void)hipFuncSetAttribute((const void*)lstm_kernel,
                              hipFuncAttributeMaxDynamicSharedMemorySize, SM_SIZE);

    pack_weights<<<1024, 128, 0, stream>>>(w_ih, w_hh, whhR, whhL, wihT);
    prep_conv_w<<<96, 256, 0, stream>>>(conv_w, wc2);
    norm_partial<<<dim3(B_N, NCHUNK), FIN, 0, stream>>>(input, part);
    conv_relu<<<dim3(B_N, 64), 256, 0, stream>>>(input, part, wc2, conv_b, X);
    x_gemm<<<dim3(B_N, 64), 256, 0, stream>>>(X, wihT, b_ih, b_hh, xg);
    lstm_kernel<<<B_N, 512, SM_SIZE, stream>>>(
        (const u32x4*)whhR, (const u32x4*)whhL, xg,
        hx0, cx0, lin_w, lin_b, (float*)d_out);
}